// Round 14
// baseline (185.866 us; speedup 1.0000x reference)
//
#include <hip/hip_runtime.h>
#include <hip/hip_fp16.h>
#include <math.h>

#define N_NODESc 100000
#define N_EDGESc 20000
#define NNZc     640000
#define FD       128
#define WE       96
#define WN       48
#define NBKT     256
#define EPB      2048
#define NCHUNKS  313   // ceil(NNZ/EPB) for hist
#define PCHUNK   1024
#define NPBLK    625   // NNZ/PCHUNK exactly
#define ESHIFT   7     // edge bucket = e>>7
#define NSHIFT   9     // node bucket = n>>9
#define NBKT_E   157   // ceil(20000/128)
#define NBKT_N   196   // ceil(100000/512)
#define STAGEBLK 6250  // N_NODES*16/256
#define NMASK    0x1FFFFu
#define MIN_NORMf 1e-5f
#define EPSf      1e-7f
#define MAX_NORMf 1e6f

// ---------- helpers ----------
__device__ __forceinline__ float wred(float v){
  #pragma unroll
  for(int m=32;m;m>>=1) v += __shfl_xor(v, m, 64);
  return v;
}
__device__ __forceinline__ void wred2_16(float& a, float& b){
  #pragma unroll
  for(int m=8;m;m>>=1){
    float ta = __shfl_xor(a, m, 64);
    float tb = __shfl_xor(b, m, 64);
    a += ta; b += tb;
  }
}

// 8 packed halves (one float4) -> accumulate into two fp32 float4s
__device__ __forceinline__ void h8_acc(const float4 h, float4& a0, float4& a1){
  const __half2* hp = (const __half2*)&h;
  float2 f0 = __half22float2(hp[0]);
  float2 f1 = __half22float2(hp[1]);
  float2 f2 = __half22float2(hp[2]);
  float2 f3 = __half22float2(hp[3]);
  a0.x += f0.x; a0.y += f0.y; a0.z += f1.x; a0.w += f1.y;
  a1.x += f2.x; a1.y += f2.y; a1.z += f3.x; a1.w += f3.y;
}
// pack two fp32 float4s -> 8 halves in one float4
__device__ __forceinline__ float4 pack_h8(const float4 a, const float4 b){
  float4 out;
  __half2* hp = (__half2*)&out;
  hp[0] = __float22half2_rn(make_float2(a.x,a.y));
  hp[1] = __float22half2_rn(make_float2(a.z,a.w));
  hp[2] = __float22half2_rn(make_float2(b.x,b.y));
  hp[3] = __float22half2_rn(make_float2(b.z,b.w));
  return out;
}

// ---------- fused prep: detect dtype + scalars/bias + zero gHist & gCur (1 block) ----------
__global__ void k_prep(const int* hei, const float* curv, const float* biases,
                       int* flag, float* scal, float* ubias, int* gHist, int* gCur){
  int tid = threadIdx.x;
  gHist[tid] = 0;  gHist[tid + NBKT] = 0;
  gCur[tid]  = 0;  gCur[tid + NBKT]  = 0;
  if(tid < 64){
    int lane = tid;
    int hi = hei[2*lane+1];
    unsigned long long b = __ballot(hi != 0);
    if(lane==0) flag[0] = (b==0ull) ? 1 : 0;
    if(lane==0){
      scal[0] = log1pf(expf(curv[0]));
      scal[1] = log1pf(expf(curv[1]));
      scal[2] = log1pf(expf(curv[2]));
    }
    int d0 = 2*lane, d1 = d0+1;
    for(int L=0; L<2; ++L){
      float u0 = (d0==0) ? 0.f : biases[L*FD + d0];
      float u1 = biases[L*FD + d1];
      ubias[L*FD + d0] = u0;
      ubias[L*FD + d1] = u1;
      float uu = wred(u0*u0 + u1*u1);
      if(lane==0) scal[3+L] = uu;
    }
  }
}

// ---------- fused: stage x->fp16 [0,x]  +  BOTH-side bucket histogram + pack (n,e)->u32 ----------
__global__ void k_stage_hist(const float* x, float4* xh,
                             const int* hei, const int* flag, int* gHist, unsigned* pk){
  int bid = blockIdx.x;
  if(bid < STAGEBLK){
    int t = bid*256 + threadIdx.x;
    int node = t >> 4, l16 = t & 15;
    int d8 = 8*l16;
    const float* r = x + (size_t)node*(FD-1);
    float4 p0, p1;
    if(l16==0){
      float4 q0 = *(const float4*)(r);
      p1 = *(const float4*)(r + 3);
      p0 = make_float4(0.f, q0.x, q0.y, q0.z);
    } else {
      p0 = *(const float4*)(r + d8 - 1);
      p1 = *(const float4*)(r + d8 + 3);
    }
    xh[(size_t)node*16 + l16] = pack_h8(p0, p1);
  } else {
    __shared__ int hE[NBKT];
    __shared__ int hN[NBKT];
    int tid = threadIdx.x;
    int chunk = bid - STAGEBLK;
    hE[tid] = 0; hN[tid] = 0; __syncthreads();
    int f64 = flag[0];
    int base = chunk*EPB;
    #pragma unroll
    for(int it=0; it<4; ++it){
      int k = base + it*512 + tid*2;    // two consecutive entries, vector loads
      if(k < NNZc){
        int n0,n1,e0,e1;
        if(f64){
          int4 aa = *(const int4*)(hei + 2*k);
          int4 bb = *(const int4*)(hei + 2*NNZc + 2*k);
          n0=aa.x; n1=aa.z; e0=bb.x; e1=bb.z;
        } else {
          int2 aa = *(const int2*)(hei + k);
          int2 bb = *(const int2*)(hei + NNZc + k);
          n0=aa.x; n1=aa.y; e0=bb.x; e1=bb.y;
        }
        atomicAdd(&hE[e0>>ESHIFT],1);
        atomicAdd(&hE[e1>>ESHIFT],1);
        atomicAdd(&hN[n0>>NSHIFT],1);
        atomicAdd(&hN[n1>>NSHIFT],1);
        uint2 pv = make_uint2(((unsigned)e0<<17)|(unsigned)n0,
                              ((unsigned)e1<<17)|(unsigned)n1);
        *(uint2*)(pk + k) = pv;
      }
    }
    __syncthreads();
    int cE = hE[tid];
    if(cE>0) atomicAdd(&gHist[tid], cE);
    int cN = hN[tid];
    if(cN>0) atomicAdd(&gHist[NBKT+tid], cN);
  }
}

// ---------- partition packed entries into BOTH bucket-contiguous stagings (scans fused) ----------
__global__ void k_part(const unsigned* pk, const int* gHist, int* gCur,
                       unsigned* partE, unsigned* partN){
  __shared__ int sscan[NBKT];
  __shared__ int hE[NBKT];
  __shared__ int hN[NBKT];
  __shared__ int bbE[NBKT];
  __shared__ int bbN[NBKT];
  int tid = threadIdx.x;
  int chunk = blockIdx.x;

  // exclusive scan of edge-side histogram
  int hvE = gHist[tid];
  sscan[tid] = hvE; hE[tid] = 0; hN[tid] = 0;
  __syncthreads();
  for(int off=1; off<NBKT; off<<=1){
    int t2 = (tid>=off)? sscan[tid-off] : 0;
    __syncthreads();
    sscan[tid] += t2;
    __syncthreads();
  }
  int sbaseE = sscan[tid] - hvE;
  __syncthreads();
  // exclusive scan of node-side histogram (reuse sscan)
  int hvN = gHist[NBKT+tid];
  sscan[tid] = hvN;
  __syncthreads();
  for(int off=1; off<NBKT; off<<=1){
    int t2 = (tid>=off)? sscan[tid-off] : 0;
    __syncthreads();
    sscan[tid] += t2;
    __syncthreads();
  }
  int sbaseN = sscan[tid] - hvN;

  int base = chunk*PCHUNK;
  int k0 = base + tid*4;                 // PCHUNK=1024 = 256*4, always in range
  uint4 v = *(const uint4*)(pk + k0);
  unsigned kv[4] = {v.x, v.y, v.z, v.w};
  int rE[4], rN[4];
  #pragma unroll
  for(int j=0;j<4;++j){
    rE[j] = atomicAdd(&hE[kv[j]>>(17+ESHIFT)], 1);
    rN[j] = atomicAdd(&hN[(kv[j]&NMASK)>>NSHIFT], 1);
  }
  __syncthreads();
  int cE = hE[tid];
  if(cE>0) bbE[tid] = sbaseE + atomicAdd(&gCur[tid], cE);
  int cN = hN[tid];
  if(cN>0) bbN[tid] = sbaseN + atomicAdd(&gCur[NBKT+tid], cN);
  __syncthreads();
  #pragma unroll
  for(int j=0;j<4;++j){
    partE[bbE[kv[j]>>(17+ESHIFT)] + rE[j]] = kv[j];
    partN[bbN[(kv[j]&NMASK)>>NSHIFT] + rN[j]] = kv[j];
  }
}

// ---------- ELL build: one block per bucket, LDS cursors, writes final counts ----------
__global__ void k_build(const unsigned* partE, const unsigned* partN,
                        const int* gHist, int* curE, int* curN, int* eEll, int* nEll){
  __shared__ int sscan[NBKT];
  __shared__ int lcur[512];
  int bid = blockIdx.x;
  int side = (bid >= NBKT_E) ? 1 : 0;
  int bkt  = side ? bid - NBKT_E : bid;
  int tid = threadIdx.x;

  // in-block exclusive scan for bucket start
  int hv = gHist[side*NBKT+tid];
  sscan[tid] = hv; __syncthreads();
  for(int off=1; off<NBKT; off<<=1){
    int t2 = (tid>=off)? sscan[tid-off] : 0;
    __syncthreads();
    sscan[tid] += t2;
    __syncthreads();
  }
  int cntB  = gHist[side*NBKT+bkt];
  int start = sscan[bkt] - cntB;

  int nkeys = side ? 512 : 128;
  for(int i=tid; i<nkeys; i+=256) lcur[i] = 0;
  __syncthreads();

  const unsigned* part = side ? partN : partE;
  int* ell = side ? nEll : eEll;
  int W = side ? WN : WE;
  int keybase = side ? (bkt<<NSHIFT) : (bkt<<ESHIFT);
  for(int i=tid; i<cntB; i+=256){
    unsigned v = part[start+i];
    int key = side ? (int)(v&NMASK) : (int)(v>>17);
    int pay = side ? (int)(v>>17)   : (int)(v&NMASK);
    int pos = atomicAdd(&lcur[key-keybase], 1);
    if(pos<W) ell[(size_t)key*W+pos] = pay;
  }
  __syncthreads();

  int total = side ? N_NODESc : N_EDGESc;
  int* cur  = side ? curN : curE;
  for(int i=tid; i<nkeys; i+=256){
    int key = keybase + i;
    if(key < total) cur[key] = lcur[i];
  }
}

// ---------- stage 1: e_feat[e] = (1/cnt)*sum rows — fp16 rows, 8 in flight/quad ----------
__global__ void k_edge_gather(const int* curE, const int* eEll, const float4* rowsH, float4* efeatH){
  int t = blockIdx.x*blockDim.x + threadIdx.x;
  int w    = t >> 6;                    // 10000 waves
  int lane = t & 63;
  int quad = lane >> 4, l16 = lane & 15;
  int edge = w*2 + (quad>>1);
  int qh   = quad & 1;                  // which half of the entry list (strided 2)

  int cnt = curE[edge];
  int use = cnt<WE ? cnt : WE;
  const int* ent = eEll + (size_t)edge*WE;

  float4 aA = make_float4(0.f,0.f,0.f,0.f);
  float4 aB = make_float4(0.f,0.f,0.f,0.f);
  int j = qh;
  for(; j+14 < use; j += 16){           // 8 rows in flight
    int r0 = ent[j];    int r1 = ent[j+2];
    int r2 = ent[j+4];  int r3 = ent[j+6];
    int r4 = ent[j+8];  int r5 = ent[j+10];
    int r6 = ent[j+12]; int r7 = ent[j+14];
    float4 h0 = rowsH[(size_t)r0*16 + l16];
    float4 h1 = rowsH[(size_t)r1*16 + l16];
    float4 h2 = rowsH[(size_t)r2*16 + l16];
    float4 h3 = rowsH[(size_t)r3*16 + l16];
    float4 h4 = rowsH[(size_t)r4*16 + l16];
    float4 h5 = rowsH[(size_t)r5*16 + l16];
    float4 h6 = rowsH[(size_t)r6*16 + l16];
    float4 h7 = rowsH[(size_t)r7*16 + l16];
    h8_acc(h0,aA,aB); h8_acc(h1,aA,aB); h8_acc(h2,aA,aB); h8_acc(h3,aA,aB);
    h8_acc(h4,aA,aB); h8_acc(h5,aA,aB); h8_acc(h6,aA,aB); h8_acc(h7,aA,aB);
  }
  for(; j < use; j += 2){
    float4 h = rowsH[(size_t)ent[j]*16 + l16];
    h8_acc(h,aA,aB);
  }
  // fold the two strided halves (quad 0<->1, 2<->3)
  aA.x += __shfl_xor(aA.x, 16, 64); aA.y += __shfl_xor(aA.y, 16, 64);
  aA.z += __shfl_xor(aA.z, 16, 64); aA.w += __shfl_xor(aA.w, 16, 64);
  aB.x += __shfl_xor(aB.x, 16, 64); aB.y += __shfl_xor(aB.y, 16, 64);
  aB.z += __shfl_xor(aB.z, 16, 64); aB.w += __shfl_xor(aB.w, 16, 64);

  if(qh==0){
    float b = cnt>0 ? __fdividef(1.f,(float)cnt) : 0.f;
    aA.x*=b; aA.y*=b; aA.z*=b; aA.w*=b;
    aB.x*=b; aB.y*=b; aB.z*=b; aB.w*=b;
    efeatH[(size_t)edge*16 + l16] = pack_h8(aA, aB);
  }
}

// ---------- stage 2 + fused hyperbolic epilogue: 4 nodes/wave, independent quads ----------
// OUTH=1: write fp16 table (next-layer input); OUTH=0: write fp32 final output
template<int OUTH>
__global__ void k_node_epilogue(const int* curN, const int* nEll, const float4* efeatH,
                                const float* scal, const float* ubias, int layer,
                                float4* outH, float* outF){
  int t = blockIdx.x*blockDim.x + threadIdx.x;
  int w    = t >> 6;
  int lane = t & 63;
  if(w >= N_NODESc/4) return;
  int quad = lane >> 4, l16 = lane & 15;
  int node = w*4 + quad;
  int d8 = 8*l16;

  float cin = scal[layer];
  float K   = __fdividef(1.f, cin);
  float sK  = sqrtf(K);
  float isK = __fdividef(1.f, sK);
  float uu  = scal[3+layer];

  int cnt = curN[node];
  float dv = cnt>0 ? __fdividef(1.f,(float)cnt) : 0.f;
  int use = cnt<WN ? cnt : WN;
  const int* ent = nEll + (size_t)node*WN;

  float4 aA = make_float4(0.f,0.f,0.f,0.f);
  float4 aB = make_float4(0.f,0.f,0.f,0.f);
  int j = 0;
  for(; j+3 < use; j += 4){             // 4 rows in flight per quad
    int r0 = ent[j];   int r1 = ent[j+1];
    int r2 = ent[j+2]; int r3 = ent[j+3];
    float4 h0 = efeatH[(size_t)r0*16 + l16];
    float4 h1 = efeatH[(size_t)r1*16 + l16];
    float4 h2 = efeatH[(size_t)r2*16 + l16];
    float4 h3 = efeatH[(size_t)r3*16 + l16];
    h8_acc(h0,aA,aB); h8_acc(h1,aA,aB); h8_acc(h2,aA,aB); h8_acc(h3,aA,aB);
  }
  for(; j < use; ++j){
    float4 h = efeatH[(size_t)ent[j]*16 + l16];
    h8_acc(h,aA,aB);
  }
  aA.x*=dv; aA.y*=dv; aA.z*=dv; aA.w*=dv;
  aB.x*=dv; aB.y*=dv; aB.z*=dv; aB.w*=dv;   // dim-0 slot exactly 0

  const float4* up = (const float4*)(ubias + layer*FD + d8);
  float4 uA = up[0], uB = up[1];

  float ysq   = aA.x*aA.x + aA.y*aA.y + aA.z*aA.z + aA.w*aA.w
              + aB.x*aB.x + aB.y*aB.y + aB.z*aB.z + aB.w*aB.w;
  float dotAU = aA.x*uA.x + aA.y*uA.y + aA.z*uA.z + aA.w*uA.w
              + aB.x*uB.x + aB.y*uB.y + aB.z*uB.z + aB.w*uB.w;
  wred2_16(ysq, dotAU);

  float res0  = sqrtf(fmaxf(K + ysq, EPSf));
  float ynorm = fmaxf(sqrtf(ysq), MIN_NORMf);
  float iyn   = __fdividef(1.f, ynorm);

  // mobius_add via ptransp0 + expmap (reduction-free by linearity)
  float alpha = dotAU*iyn*isK;
  float ab    = alpha*(sK - res0);
  float abiyn = ab*iyn;
  float4 rA, rB;
  rA.x = fmaf(-abiyn, aA.x, uA.x); rA.y = fmaf(-abiyn, aA.y, uA.y);
  rA.z = fmaf(-abiyn, aA.z, uA.z); rA.w = fmaf(-abiyn, aA.w, uA.w);
  rB.x = fmaf(-abiyn, aB.x, uB.x); rB.y = fmaf(-abiyn, aB.y, uB.y);
  rB.z = fmaf(-abiyn, aB.z, uB.z); rB.w = fmaf(-abiyn, aB.w, uB.w);
  float ux  = fmaf(-ab, ynorm, dotAU);
  float v0s = ux * __fdividef(1.f, fmaxf(res0, EPSf));
  float rsq = fmaf(ab, ab, fmaf(-2.f*abiyn, dotAU, uu));

  float mink  = fmaxf(fmaf(-v0s, v0s, rsq), EPSf);
  float normu = fminf(sqrtf(mink), MAX_NORMf);
  float th    = fmaxf(normu*isK, MIN_NORMf);
  float thc   = fminf(th, 15.f);
  float e  = __expf(thc);
  float ei = __fdividef(1.f, e);
  float ch = 0.5f*(e + ei);
  float sh = 0.5f*(e - ei);
  float sth = sh*__fdividef(1.f, th);
  float4 qA, qB;
  qA.x = fmaf(ch, aA.x, sth*rA.x); qA.y = fmaf(ch, aA.y, sth*rA.y);
  qA.z = fmaf(ch, aA.z, sth*rA.z); qA.w = fmaf(ch, aA.w, sth*rA.w);
  qB.x = fmaf(ch, aB.x, sth*rB.x); qB.y = fmaf(ch, aB.y, sth*rB.y);
  qB.z = fmaf(ch, aB.z, sth*rB.z); qB.w = fmaf(ch, aB.w, sth*rB.w);

  float ysq2 = fmaxf(ch*ch*ysq + 2.f*ch*sth*ux + sth*sth*rsq, 0.f);
  float h0   = sqrtf(fmaxf(K + ysq2, EPSf));
  float yn3  = fmaxf(sqrtf(ysq2), MIN_NORMf);
  float th3  = fmaxf(h0*isK, 1.f+EPSf);
  float acs  = __logf(th3 + sqrtf(fmaxf(fmaf(th3,th3,-1.f), EPSf)));
  float fac  = sK*acs*__fdividef(1.f, yn3);
  float4 tA, tB;
  tA.x = fac*qA.x; tA.y = fac*qA.y; tA.z = fac*qA.z; tA.w = fac*qA.w;
  tB.x = fac*qB.x; tB.y = fac*qB.y; tB.z = fac*qB.z; tB.w = fac*qB.w;
  tA.x = tA.x>=0.f ? tA.x : 0.01f*tA.x;
  tA.y = tA.y>=0.f ? tA.y : 0.01f*tA.y;
  tA.z = tA.z>=0.f ? tA.z : 0.01f*tA.z;
  tA.w = tA.w>=0.f ? tA.w : 0.01f*tA.w;
  tB.x = tB.x>=0.f ? tB.x : 0.01f*tB.x;
  tB.y = tB.y>=0.f ? tB.y : 0.01f*tB.y;
  tB.z = tB.z>=0.f ? tB.z : 0.01f*tB.z;
  tB.w = tB.w>=0.f ? tB.w : 0.01f*tB.w;
  if(l16==0) tA.x = 0.f;

  if(OUTH){
    outH[(size_t)node*16 + l16] = pack_h8(tA, tB);
  } else {
    float4* op = (float4*)(outF + (size_t)node*FD + d8);
    op[0] = tA;
    op[1] = tB;
  }
}

// ---------- launch ----------
extern "C" void kernel_launch(void* const* d_in, const int* in_sizes, int n_in,
                              void* d_out, int out_size, void* d_ws, size_t ws_size,
                              hipStream_t stream) {
  const float* x      = (const float*)d_in[0];
  const int*   hei    = (const int*)d_in[1];
  const float* curv   = (const float*)d_in[2];
  const float* biases = (const float*)d_in[3];
  float* out = (float*)d_out;

  char* p = (char*)d_ws;
  auto alloc = [&](size_t bytes){ char* r = p; p += (bytes + 255) & ~(size_t)255; return r; };
  int*   flag  = (int*)  alloc(4);
  float* scal  = (float*)alloc(16*4);
  float* ubias = (float*)alloc(2*FD*4);
  int*   gHist = (int*)  alloc(2*NBKT*4);
  int*   gCur  = (int*)  alloc(2*NBKT*4);
  int*   curE  = (int*)  alloc((size_t)N_EDGESc*4);
  int*   curN  = (int*)  alloc((size_t)N_NODESc*4);
  unsigned* pk    = (unsigned*)alloc((size_t)NNZc*4);
  unsigned* partE = (unsigned*)alloc((size_t)NNZc*4);
  unsigned* partN = (unsigned*)alloc((size_t)NNZc*4);
  int*   eEll  = (int*)  alloc((size_t)N_EDGESc*WE*4);
  int*   nEll  = (int*)  alloc((size_t)N_NODESc*WN*4);
  float4* xh    = (float4*)alloc((size_t)N_NODESc*16*16);   // fp16 rows, 256B each
  float4* tangH = (float4*)alloc((size_t)N_NODESc*16*16);
  float4* efeatH= (float4*)alloc((size_t)N_EDGESc*16*16);

  k_prep      <<<1, 256, 0, stream>>>(hei, curv, biases, flag, scal, ubias, gHist, gCur);
  k_stage_hist<<<STAGEBLK + NCHUNKS, 256, 0, stream>>>(x, xh, hei, flag, gHist, pk);
  k_part      <<<NPBLK, 256, 0, stream>>>(pk, gHist, gCur, partE, partN);
  k_build     <<<NBKT_E + NBKT_N, 256, 0, stream>>>(partE, partN, gHist, curE, curN, eEll, nEll);

  k_edge_gather     <<<(N_EDGESc/2*64)/256, 256, 0, stream>>>(curE, eEll, xh, efeatH);
  k_node_epilogue<1><<<(N_NODESc/4*64)/256, 256, 0, stream>>>(curN, nEll, efeatH, scal, ubias, 0, tangH, out);
  k_edge_gather     <<<(N_EDGESc/2*64)/256, 256, 0, stream>>>(curE, eEll, tangH, efeatH);
  k_node_epilogue<0><<<(N_NODESc/4*64)/256, 256, 0, stream>>>(curN, nEll, efeatH, scal, ubias, 1, tangH, out);
}

// Round 15
// 177.232 us; speedup vs baseline: 1.0487x; 1.0487x over previous
//
#include <hip/hip_runtime.h>
#include <hip/hip_fp16.h>
#include <math.h>

#define N_NODESc 100000
#define N_EDGESc 20000
#define NNZc     640000
#define FD       128
#define WE       96
#define WN       48
#define NBKT     256
#define EPB      2048
#define NCHUNKS  313   // ceil(NNZ/EPB)
#define ESHIFT   7     // edge bucket = e>>7
#define NSHIFT   9     // node bucket = n>>9
#define NBKT_E   157   // ceil(20000/128)
#define NBKT_N   196   // ceil(100000/512)
#define STAGEBLK 6250  // N_NODES*16/256
#define NMASK    0x1FFFFu
#define MIN_NORMf 1e-5f
#define EPSf      1e-7f
#define MAX_NORMf 1e6f

// ---------- helpers ----------
__device__ __forceinline__ float wred(float v){
  #pragma unroll
  for(int m=32;m;m>>=1) v += __shfl_xor(v, m, 64);
  return v;
}
__device__ __forceinline__ void wred2_16(float& a, float& b){
  #pragma unroll
  for(int m=8;m;m>>=1){
    float ta = __shfl_xor(a, m, 64);
    float tb = __shfl_xor(b, m, 64);
    a += ta; b += tb;
  }
}

// 8 packed halves (one float4) -> accumulate into two fp32 float4s
__device__ __forceinline__ void h8_acc(const float4 h, float4& a0, float4& a1){
  const __half2* hp = (const __half2*)&h;
  float2 f0 = __half22float2(hp[0]);
  float2 f1 = __half22float2(hp[1]);
  float2 f2 = __half22float2(hp[2]);
  float2 f3 = __half22float2(hp[3]);
  a0.x += f0.x; a0.y += f0.y; a0.z += f1.x; a0.w += f1.y;
  a1.x += f2.x; a1.y += f2.y; a1.z += f3.x; a1.w += f3.y;
}
// pack two fp32 float4s -> 8 halves in one float4
__device__ __forceinline__ float4 pack_h8(const float4 a, const float4 b){
  float4 out;
  __half2* hp = (__half2*)&out;
  hp[0] = __float22half2_rn(make_float2(a.x,a.y));
  hp[1] = __float22half2_rn(make_float2(a.z,a.w));
  hp[2] = __float22half2_rn(make_float2(b.x,b.y));
  hp[3] = __float22half2_rn(make_float2(b.z,b.w));
  return out;
}

// ---------- fused prep: detect dtype + scalars/bias + zero gHist & gCur (1 block) ----------
__global__ void k_prep(const int* hei, const float* curv, const float* biases,
                       int* flag, float* scal, float* ubias, int* gHist, int* gCur){
  int tid = threadIdx.x;
  gHist[tid] = 0;  gHist[tid + NBKT] = 0;
  gCur[tid]  = 0;  gCur[tid + NBKT]  = 0;
  if(tid < 64){
    int lane = tid;
    int hi = hei[2*lane+1];
    unsigned long long b = __ballot(hi != 0);
    if(lane==0) flag[0] = (b==0ull) ? 1 : 0;
    if(lane==0){
      scal[0] = log1pf(expf(curv[0]));
      scal[1] = log1pf(expf(curv[1]));
      scal[2] = log1pf(expf(curv[2]));
    }
    int d0 = 2*lane, d1 = d0+1;
    for(int L=0; L<2; ++L){
      float u0 = (d0==0) ? 0.f : biases[L*FD + d0];
      float u1 = biases[L*FD + d1];
      ubias[L*FD + d0] = u0;
      ubias[L*FD + d1] = u1;
      float uu = wred(u0*u0 + u1*u1);
      if(lane==0) scal[3+L] = uu;
    }
  }
}

// ---------- fused: stage x->fp16 [0,x]  +  bucket histogram + pack (n,e)->u32 ----------
__global__ void k_stage_hist(const float* x, float4* xh,
                             const int* hei, const int* flag, int* gHist, unsigned* pk){
  int bid = blockIdx.x;
  if(bid < STAGEBLK){
    int t = bid*256 + threadIdx.x;
    int node = t >> 4, l16 = t & 15;
    int d8 = 8*l16;
    const float* r = x + (size_t)node*(FD-1);
    float4 p0, p1;
    if(l16==0){
      float4 q0 = *(const float4*)(r);
      p1 = *(const float4*)(r + 3);
      p0 = make_float4(0.f, q0.x, q0.y, q0.z);
    } else {
      p0 = *(const float4*)(r + d8 - 1);
      p1 = *(const float4*)(r + d8 + 3);
    }
    xh[(size_t)node*16 + l16] = pack_h8(p0, p1);
  } else {
    __shared__ int h[NBKT];
    int tid = threadIdx.x;
    int hb = bid - STAGEBLK;
    int side = hb & 1;
    int chunk = hb >> 1;
    h[tid] = 0; __syncthreads();
    int f64 = flag[0];
    int base = chunk*EPB;
    #pragma unroll
    for(int it=0; it<4; ++it){
      int k = base + it*512 + tid*2;    // two consecutive entries, vector loads
      if(k < NNZc){
        int n0,n1,e0,e1;
        if(f64){
          int4 aa = *(const int4*)(hei + 2*k);
          int4 bb = *(const int4*)(hei + 2*NNZc + 2*k);
          n0=aa.x; n1=aa.z; e0=bb.x; e1=bb.z;
        } else {
          int2 aa = *(const int2*)(hei + k);
          int2 bb = *(const int2*)(hei + NNZc + k);
          n0=aa.x; n1=aa.y; e0=bb.x; e1=bb.y;
        }
        if(side==0){
          atomicAdd(&h[e0>>ESHIFT],1);
          atomicAdd(&h[e1>>ESHIFT],1);
          uint2 pv = make_uint2(((unsigned)e0<<17)|(unsigned)n0,
                                ((unsigned)e1<<17)|(unsigned)n1);
          *(uint2*)(pk + k) = pv;
        } else {
          atomicAdd(&h[n0>>NSHIFT],1);
          atomicAdd(&h[n1>>NSHIFT],1);
        }
      }
    }
    __syncthreads();
    int c = h[tid];
    if(c>0) atomicAdd(&gHist[side*NBKT+tid], c);
  }
}

// ---------- partition packed entries into bucket-contiguous staging (scan fused) ----------
__global__ void k_part(const unsigned* pk, const int* gHist, int* gCur,
                       unsigned* partE, unsigned* partN){
  __shared__ int sscan[NBKT];
  __shared__ int h[NBKT];
  __shared__ int bbase[NBKT];
  int tid = threadIdx.x;
  int side = blockIdx.x & 1;
  int chunk = blockIdx.x >> 1;

  // in-block exclusive scan of this side's 256-bucket histogram
  int hv = gHist[side*NBKT+tid];
  sscan[tid] = hv;
  h[tid] = 0;
  __syncthreads();
  for(int off=1; off<NBKT; off<<=1){
    int t2 = (tid>=off)? sscan[tid-off] : 0;
    __syncthreads();
    sscan[tid] += t2;
    __syncthreads();
  }
  int sbase = sscan[tid] - hv;          // exclusive bucket base

  int base = chunk*EPB;
  unsigned kv[8]; int rank[8], bkt[8];
  #pragma unroll
  for(int it=0; it<2; ++it){
    int k = base + it*1024 + tid*4;
    bool ok = k < NNZc;
    uint4 v = ok ? *(const uint4*)(pk + k) : make_uint4(0,0,0,0);
    kv[it*4+0]=v.x; kv[it*4+1]=v.y; kv[it*4+2]=v.z; kv[it*4+3]=v.w;
    #pragma unroll
    for(int j=0;j<4;++j){
      int idx = it*4+j;
      if(ok){
        bkt[idx] = side ? (int)((kv[idx]&NMASK)>>NSHIFT) : (int)(kv[idx]>>(17+ESHIFT));
        rank[idx] = atomicAdd(&h[bkt[idx]],1);
      } else bkt[idx] = -1;
    }
  }
  __syncthreads();
  int c = h[tid];
  if(c>0) bbase[tid] = sbase + atomicAdd(&gCur[side*NBKT+tid], c);
  __syncthreads();
  unsigned* part = side ? partN : partE;
  #pragma unroll
  for(int j=0;j<8;++j){
    if(bkt[j]>=0){
      int pos = bbase[bkt[j]] + rank[j];
      part[pos] = kv[j];
    }
  }
}

// ---------- ELL build: one block per bucket, LDS cursors, writes final counts ----------
__global__ void k_build(const unsigned* partE, const unsigned* partN,
                        const int* gHist, int* curE, int* curN, int* eEll, int* nEll){
  __shared__ int sscan[NBKT];
  __shared__ int lcur[512];
  int bid = blockIdx.x;
  int side = (bid >= NBKT_E) ? 1 : 0;
  int bkt  = side ? bid - NBKT_E : bid;
  int tid = threadIdx.x;

  // in-block exclusive scan for bucket start
  int hv = gHist[side*NBKT+tid];
  sscan[tid] = hv; __syncthreads();
  for(int off=1; off<NBKT; off<<=1){
    int t2 = (tid>=off)? sscan[tid-off] : 0;
    __syncthreads();
    sscan[tid] += t2;
    __syncthreads();
  }
  int cntB  = gHist[side*NBKT+bkt];
  int start = sscan[bkt] - cntB;

  int nkeys = side ? 512 : 128;
  for(int i=tid; i<nkeys; i+=256) lcur[i] = 0;
  __syncthreads();

  const unsigned* part = side ? partN : partE;
  int* ell = side ? nEll : eEll;
  int W = side ? WN : WE;
  int keybase = side ? (bkt<<NSHIFT) : (bkt<<ESHIFT);
  for(int i=tid; i<cntB; i+=256){
    unsigned v = part[start+i];
    int key = side ? (int)(v&NMASK) : (int)(v>>17);
    int pay = side ? (int)(v>>17)   : (int)(v&NMASK);
    int pos = atomicAdd(&lcur[key-keybase], 1);
    if(pos<W) ell[(size_t)key*W+pos] = pay;
  }
  __syncthreads();

  int total = side ? N_NODESc : N_EDGESc;
  int* cur  = side ? curN : curE;
  for(int i=tid; i<nkeys; i+=256){
    int key = keybase + i;
    if(key < total) cur[key] = lcur[i];
  }
}

// ---------- stage 1: e_feat[e] = (1/cnt)*sum rows — fp16 rows, 8 in flight/quad ----------
__global__ void k_edge_gather(const int* curE, const int* eEll, const float4* rowsH, float4* efeatH){
  int t = blockIdx.x*blockDim.x + threadIdx.x;
  int w    = t >> 6;                    // 10000 waves
  int lane = t & 63;
  int quad = lane >> 4, l16 = lane & 15;
  int edge = w*2 + (quad>>1);
  int qh   = quad & 1;                  // which half of the entry list (strided 2)

  int cnt = curE[edge];
  int use = cnt<WE ? cnt : WE;
  const int* ent = eEll + (size_t)edge*WE;

  float4 aA = make_float4(0.f,0.f,0.f,0.f);
  float4 aB = make_float4(0.f,0.f,0.f,0.f);
  int j = qh;
  for(; j+14 < use; j += 16){           // 8 rows in flight
    int r0 = ent[j];    int r1 = ent[j+2];
    int r2 = ent[j+4];  int r3 = ent[j+6];
    int r4 = ent[j+8];  int r5 = ent[j+10];
    int r6 = ent[j+12]; int r7 = ent[j+14];
    float4 h0 = rowsH[(size_t)r0*16 + l16];
    float4 h1 = rowsH[(size_t)r1*16 + l16];
    float4 h2 = rowsH[(size_t)r2*16 + l16];
    float4 h3 = rowsH[(size_t)r3*16 + l16];
    float4 h4 = rowsH[(size_t)r4*16 + l16];
    float4 h5 = rowsH[(size_t)r5*16 + l16];
    float4 h6 = rowsH[(size_t)r6*16 + l16];
    float4 h7 = rowsH[(size_t)r7*16 + l16];
    h8_acc(h0,aA,aB); h8_acc(h1,aA,aB); h8_acc(h2,aA,aB); h8_acc(h3,aA,aB);
    h8_acc(h4,aA,aB); h8_acc(h5,aA,aB); h8_acc(h6,aA,aB); h8_acc(h7,aA,aB);
  }
  for(; j < use; j += 2){
    float4 h = rowsH[(size_t)ent[j]*16 + l16];
    h8_acc(h,aA,aB);
  }
  // fold the two strided halves (quad 0<->1, 2<->3)
  aA.x += __shfl_xor(aA.x, 16, 64); aA.y += __shfl_xor(aA.y, 16, 64);
  aA.z += __shfl_xor(aA.z, 16, 64); aA.w += __shfl_xor(aA.w, 16, 64);
  aB.x += __shfl_xor(aB.x, 16, 64); aB.y += __shfl_xor(aB.y, 16, 64);
  aB.z += __shfl_xor(aB.z, 16, 64); aB.w += __shfl_xor(aB.w, 16, 64);

  if(qh==0){
    float b = cnt>0 ? __fdividef(1.f,(float)cnt) : 0.f;
    aA.x*=b; aA.y*=b; aA.z*=b; aA.w*=b;
    aB.x*=b; aB.y*=b; aB.z*=b; aB.w*=b;
    efeatH[(size_t)edge*16 + l16] = pack_h8(aA, aB);
  }
}

// ---------- stage 2 + fused hyperbolic epilogue: 4 nodes/wave, independent quads ----------
// OUTH=1: write fp16 table (next-layer input); OUTH=0: write fp32 final output
template<int OUTH>
__global__ void k_node_epilogue(const int* curN, const int* nEll, const float4* efeatH,
                                const float* scal, const float* ubias, int layer,
                                float4* outH, float* outF){
  int t = blockIdx.x*blockDim.x + threadIdx.x;
  int w    = t >> 6;
  int lane = t & 63;
  if(w >= N_NODESc/4) return;
  int quad = lane >> 4, l16 = lane & 15;
  int node = w*4 + quad;
  int d8 = 8*l16;

  float cin = scal[layer];
  float K   = __fdividef(1.f, cin);
  float sK  = sqrtf(K);
  float isK = __fdividef(1.f, sK);
  float uu  = scal[3+layer];

  int cnt = curN[node];
  float dv = cnt>0 ? __fdividef(1.f,(float)cnt) : 0.f;
  int use = cnt<WN ? cnt : WN;
  const int* ent = nEll + (size_t)node*WN;

  float4 aA = make_float4(0.f,0.f,0.f,0.f);
  float4 aB = make_float4(0.f,0.f,0.f,0.f);
  int j = 0;
  for(; j+3 < use; j += 4){             // 4 rows in flight per quad
    int r0 = ent[j];   int r1 = ent[j+1];
    int r2 = ent[j+2]; int r3 = ent[j+3];
    float4 h0 = efeatH[(size_t)r0*16 + l16];
    float4 h1 = efeatH[(size_t)r1*16 + l16];
    float4 h2 = efeatH[(size_t)r2*16 + l16];
    float4 h3 = efeatH[(size_t)r3*16 + l16];
    h8_acc(h0,aA,aB); h8_acc(h1,aA,aB); h8_acc(h2,aA,aB); h8_acc(h3,aA,aB);
  }
  for(; j < use; ++j){
    float4 h = efeatH[(size_t)ent[j]*16 + l16];
    h8_acc(h,aA,aB);
  }
  aA.x*=dv; aA.y*=dv; aA.z*=dv; aA.w*=dv;
  aB.x*=dv; aB.y*=dv; aB.z*=dv; aB.w*=dv;   // dim-0 slot exactly 0

  const float4* up = (const float4*)(ubias + layer*FD + d8);
  float4 uA = up[0], uB = up[1];

  float ysq   = aA.x*aA.x + aA.y*aA.y + aA.z*aA.z + aA.w*aA.w
              + aB.x*aB.x + aB.y*aB.y + aB.z*aB.z + aB.w*aB.w;
  float dotAU = aA.x*uA.x + aA.y*uA.y + aA.z*uA.z + aA.w*uA.w
              + aB.x*uB.x + aB.y*uB.y + aB.z*uB.z + aB.w*uB.w;
  wred2_16(ysq, dotAU);

  float res0  = sqrtf(fmaxf(K + ysq, EPSf));
  float ynorm = fmaxf(sqrtf(ysq), MIN_NORMf);
  float iyn   = __fdividef(1.f, ynorm);

  // mobius_add via ptransp0 + expmap (reduction-free by linearity)
  float alpha = dotAU*iyn*isK;
  float ab    = alpha*(sK - res0);
  float abiyn = ab*iyn;
  float4 rA, rB;
  rA.x = fmaf(-abiyn, aA.x, uA.x); rA.y = fmaf(-abiyn, aA.y, uA.y);
  rA.z = fmaf(-abiyn, aA.z, uA.z); rA.w = fmaf(-abiyn, aA.w, uA.w);
  rB.x = fmaf(-abiyn, aB.x, uB.x); rB.y = fmaf(-abiyn, aB.y, uB.y);
  rB.z = fmaf(-abiyn, aB.z, uB.z); rB.w = fmaf(-abiyn, aB.w, uB.w);
  float ux  = fmaf(-ab, ynorm, dotAU);
  float v0s = ux * __fdividef(1.f, fmaxf(res0, EPSf));
  float rsq = fmaf(ab, ab, fmaf(-2.f*abiyn, dotAU, uu));

  float mink  = fmaxf(fmaf(-v0s, v0s, rsq), EPSf);
  float normu = fminf(sqrtf(mink), MAX_NORMf);
  float th    = fmaxf(normu*isK, MIN_NORMf);
  float thc   = fminf(th, 15.f);
  float e  = __expf(thc);
  float ei = __fdividef(1.f, e);
  float ch = 0.5f*(e + ei);
  float sh = 0.5f*(e - ei);
  float sth = sh*__fdividef(1.f, th);
  float4 qA, qB;
  qA.x = fmaf(ch, aA.x, sth*rA.x); qA.y = fmaf(ch, aA.y, sth*rA.y);
  qA.z = fmaf(ch, aA.z, sth*rA.z); qA.w = fmaf(ch, aA.w, sth*rA.w);
  qB.x = fmaf(ch, aB.x, sth*rB.x); qB.y = fmaf(ch, aB.y, sth*rB.y);
  qB.z = fmaf(ch, aB.z, sth*rB.z); qB.w = fmaf(ch, aB.w, sth*rB.w);

  float ysq2 = fmaxf(ch*ch*ysq + 2.f*ch*sth*ux + sth*sth*rsq, 0.f);
  float h0   = sqrtf(fmaxf(K + ysq2, EPSf));
  float yn3  = fmaxf(sqrtf(ysq2), MIN_NORMf);
  float th3  = fmaxf(h0*isK, 1.f+EPSf);
  float acs  = __logf(th3 + sqrtf(fmaxf(fmaf(th3,th3,-1.f), EPSf)));
  float fac  = sK*acs*__fdividef(1.f, yn3);
  float4 tA, tB;
  tA.x = fac*qA.x; tA.y = fac*qA.y; tA.z = fac*qA.z; tA.w = fac*qA.w;
  tB.x = fac*qB.x; tB.y = fac*qB.y; tB.z = fac*qB.z; tB.w = fac*qB.w;
  tA.x = tA.x>=0.f ? tA.x : 0.01f*tA.x;
  tA.y = tA.y>=0.f ? tA.y : 0.01f*tA.y;
  tA.z = tA.z>=0.f ? tA.z : 0.01f*tA.z;
  tA.w = tA.w>=0.f ? tA.w : 0.01f*tA.w;
  tB.x = tB.x>=0.f ? tB.x : 0.01f*tB.x;
  tB.y = tB.y>=0.f ? tB.y : 0.01f*tB.y;
  tB.z = tB.z>=0.f ? tB.z : 0.01f*tB.z;
  tB.w = tB.w>=0.f ? tB.w : 0.01f*tB.w;
  if(l16==0) tA.x = 0.f;

  if(OUTH){
    outH[(size_t)node*16 + l16] = pack_h8(tA, tB);
  } else {
    float4* op = (float4*)(outF + (size_t)node*FD + d8);
    op[0] = tA;
    op[1] = tB;
  }
}

// ---------- launch ----------
extern "C" void kernel_launch(void* const* d_in, const int* in_sizes, int n_in,
                              void* d_out, int out_size, void* d_ws, size_t ws_size,
                              hipStream_t stream) {
  const float* x      = (const float*)d_in[0];
  const int*   hei    = (const int*)d_in[1];
  const float* curv   = (const float*)d_in[2];
  const float* biases = (const float*)d_in[3];
  float* out = (float*)d_out;

  char* p = (char*)d_ws;
  auto alloc = [&](size_t bytes){ char* r = p; p += (bytes + 255) & ~(size_t)255; return r; };
  int*   flag  = (int*)  alloc(4);
  float* scal  = (float*)alloc(16*4);
  float* ubias = (float*)alloc(2*FD*4);
  int*   gHist = (int*)  alloc(2*NBKT*4);
  int*   gCur  = (int*)  alloc(2*NBKT*4);
  int*   curE  = (int*)  alloc((size_t)N_EDGESc*4);
  int*   curN  = (int*)  alloc((size_t)N_NODESc*4);
  unsigned* pk    = (unsigned*)alloc((size_t)NNZc*4);
  unsigned* partE = (unsigned*)alloc((size_t)NNZc*4);
  unsigned* partN = (unsigned*)alloc((size_t)NNZc*4);
  int*   eEll  = (int*)  alloc((size_t)N_EDGESc*WE*4);
  int*   nEll  = (int*)  alloc((size_t)N_NODESc*WN*4);
  float4* xh    = (float4*)alloc((size_t)N_NODESc*16*16);   // fp16 rows, 256B each
  float4* tangH = (float4*)alloc((size_t)N_NODESc*16*16);
  float4* efeatH= (float4*)alloc((size_t)N_EDGESc*16*16);

  k_prep      <<<1, 256, 0, stream>>>(hei, curv, biases, flag, scal, ubias, gHist, gCur);
  k_stage_hist<<<STAGEBLK + 2*NCHUNKS, 256, 0, stream>>>(x, xh, hei, flag, gHist, pk);
  k_part      <<<2*NCHUNKS, 256, 0, stream>>>(pk, gHist, gCur, partE, partN);
  k_build     <<<NBKT_E + NBKT_N, 256, 0, stream>>>(partE, partN, gHist, curE, curN, eEll, nEll);

  k_edge_gather     <<<(N_EDGESc/2*64)/256, 256, 0, stream>>>(curE, eEll, xh, efeatH);
  k_node_epilogue<1><<<(N_NODESc/4*64)/256, 256, 0, stream>>>(curN, nEll, efeatH, scal, ubias, 0, tangH, out);
  k_edge_gather     <<<(N_EDGESc/2*64)/256, 256, 0, stream>>>(curE, eEll, tangH, efeatH);
  k_node_epilogue<0><<<(N_NODESc/4*64)/256, 256, 0, stream>>>(curN, nEll, efeatH, scal, ubias, 1, tangH, out);
}